// Round 3
// baseline (19294.575 us; speedup 1.0000x reference)
//
#include <hip/hip_runtime.h>
#include <cstdint>
#include <cstddef>

// ============================================================================
// PointerNet: encoder LSTM (B=512,S=256,D=2,H=256) + autoregressive pointer
// decode with jax.random.categorical (threefry2x32 partitionable, key 42).
// Output: int32 indices [512][256], trajectory-exact vs JAX reference.
//
// R3 structure: block = 1024 threads = 2 batches x 256 units x 2 K-halves
// (K split inside each wave: lanes 0..31 -> k 0..127, lanes 32..63 ->
// k 128..255, combined via one __shfl_xor(32)). Grid = 256 blocks (1/CU),
// 16 waves/CU. No nontemporal hints (R2's nt loads forced ~16.6 GB of HBM
// fetch); encK4 attention stream is served by L2/L3. Weights repacked
// [k][u][4 gates] float4 in ws; h double-buffered in LDS; cell state c in
// registers (duplicated across the two K-half lanes, identical arithmetic).
// ============================================================================

typedef float v4f __attribute__((ext_vector_type(4)));

#define WS_ENCW4_OFF  (2u << 20)                    // [256 k][256 u][4 g] f32
#define WS_DECWI4_OFF (3u << 20)
#define WS_DECWH4_OFF (4u << 20)
#define WS_ENCK4_OFF  (5u << 20)                    // [512 b][64 u4][256 s][4] f32
#define WS_NEEDED     ((size_t)(5u << 20) + (size_t)512 * 64 * 256 * 16)

__device__ __forceinline__ unsigned rotl32(unsigned x, int r) {
  return (x << r) | (x >> (32 - r));
}
__device__ __forceinline__ float sigm(float x) { return 1.f / (1.f + expf(-x)); }

// Threefry-2x32, 20 rounds (jax._src.prng schedule) — verified exact in R1/R2.
__device__ __forceinline__ void tf2(unsigned k0, unsigned k1,
                                    unsigned& x0, unsigned& x1) {
  const unsigned k2 = k0 ^ k1 ^ 0x1BD11BDAu;
  x0 += k0; x1 += k1;
  x0 += x1; x1 = rotl32(x1, 13); x1 ^= x0;
  x0 += x1; x1 = rotl32(x1, 15); x1 ^= x0;
  x0 += x1; x1 = rotl32(x1, 26); x1 ^= x0;
  x0 += x1; x1 = rotl32(x1,  6); x1 ^= x0;
  x0 += k1; x1 += k2 + 1u;
  x0 += x1; x1 = rotl32(x1, 17); x1 ^= x0;
  x0 += x1; x1 = rotl32(x1, 29); x1 ^= x0;
  x0 += x1; x1 = rotl32(x1, 16); x1 ^= x0;
  x0 += x1; x1 = rotl32(x1, 24); x1 ^= x0;
  x0 += k2; x1 += k0 + 2u;
  x0 += x1; x1 = rotl32(x1, 13); x1 ^= x0;
  x0 += x1; x1 = rotl32(x1, 15); x1 ^= x0;
  x0 += x1; x1 = rotl32(x1, 26); x1 ^= x0;
  x0 += x1; x1 = rotl32(x1,  6); x1 ^= x0;
  x0 += k0; x1 += k1 + 3u;
  x0 += x1; x1 = rotl32(x1, 17); x1 ^= x0;
  x0 += x1; x1 = rotl32(x1, 29); x1 ^= x0;
  x0 += x1; x1 = rotl32(x1, 16); x1 ^= x0;
  x0 += x1; x1 = rotl32(x1, 24); x1 ^= x0;
  x0 += k1; x1 += k2 + 4u;
  x0 += x1; x1 = rotl32(x1, 13); x1 ^= x0;
  x0 += x1; x1 = rotl32(x1, 15); x1 ^= x0;
  x0 += x1; x1 = rotl32(x1, 26); x1 ^= x0;
  x0 += x1; x1 = rotl32(x1,  6); x1 ^= x0;
  x0 += k2; x1 += k0 + 5u;
}

// Repack W [1024 rows][256 k] row-major -> [k][u][gate] (float4 per (k,u)).
__global__ void repack_k(const float* __restrict__ eWh,
                         const float* __restrict__ dWi,
                         const float* __restrict__ dWh,
                         float* __restrict__ ws) {
  float* encW4 = (float*)((char*)ws + WS_ENCW4_OFF);
  float* decWi4 = (float*)((char*)ws + WS_DECWI4_OFF);
  float* decWh4 = (float*)((char*)ws + WS_DECWH4_OFF);
  const int n = blockIdx.x * blockDim.x + threadIdx.x;   // 65536 = 256k x 256u
  if (n >= 65536) return;
  const int k = n >> 8, u = n & 255;
#pragma unroll
  for (int g = 0; g < 4; ++g) {
    const int src = ((g << 8) + u) * 256 + k;
    const int dst = (n << 2) + g;
    encW4[dst] = eWh[src];
    decWi4[dst] = dWi[src];
    decWh4[dst] = dWh[src];
  }
}

__global__ void __launch_bounds__(1024)
ptrnet_kernel(const float* __restrict__ inp,    // [512][256][2]
              const float* __restrict__ eWi,    // [1024][2]
              const float* __restrict__ eBi, const float* __restrict__ eBh,
              const float* __restrict__ dBi, const float* __restrict__ dBh,
              int* __restrict__ out,            // [512][256]
              float* __restrict__ ws) {
  const int tid = threadIdx.x;
  const int wave = tid >> 6;            // 0..15
  const int bl = wave >> 3;             // batch within block (0/1)
  const int wl = wave & 7;              // wave within batch (u-slice of 32)
  const int l  = tid & 63;
  const int lk = l >> 5;                // K-half (0: k 0..127, 1: k 128..255)
  const int lu = l & 31;
  const int u  = (wl << 5) | lu;        // unit / score position 0..255
  const int b  = (blockIdx.x << 1) + bl;

  const v4f* encW4  = (const v4f*)((char*)ws + WS_ENCW4_OFF);
  const v4f* decWi4 = (const v4f*)((char*)ws + WS_DECWI4_OFF);
  const v4f* decWh4 = (const v4f*)((char*)ws + WS_DECWH4_OFF);
  v4f* encK4 = (v4f*)((char*)ws + WS_ENCK4_OFF);

  __shared__ __align__(16) float hsF[2][2][256];   // [buf][bl][u]
  __shared__ __align__(16) float dinF[2][256];     // [bl][k]
  __shared__ unsigned char maskC[2][256];
  __shared__ float partV[2][8];
  __shared__ int   partI[2][8];
  __shared__ int   idxS[2];

  // ---- per-lane constants for unit u ----
  const float ebi_ = eBi[u] + eBh[u];
  const float ebf_ = eBi[256 + u] + eBh[256 + u];
  const float ebg_ = eBi[512 + u] + eBh[512 + u];
  const float ebo_ = eBi[768 + u] + eBh[768 + u];
  const float wxi0 = eWi[2 * u], wxi1 = eWi[2 * u + 1];
  const float wxf0 = eWi[2 * (256 + u)], wxf1 = eWi[2 * (256 + u) + 1];
  const float wxg0 = eWi[2 * (512 + u)], wxg1 = eWi[2 * (512 + u) + 1];
  const float wxo0 = eWi[2 * (768 + u)], wxo1 = eWi[2 * (768 + u) + 1];

  if (tid < 512) hsF[0][tid >> 8][tid & 255] = 0.f;
  __syncthreads();

  float c = 0.f;        // cell state for (b,u); identical copy in both K-halves
  int p = 0;            // h read-buffer parity
  const int kbase = lk << 5;            // first k4 of this lane's K-half

  // ---------------- encoder: 256 steps ----------------
  for (int t = 0; t < 256; ++t) {
    const float2 xv = *(const float2*)(inp + ((b << 8) + t) * 2);
    float ai = 0.f, af = 0.f, ag = 0.f, ao = 0.f;
    const v4f* Wp = encW4 + u;
    const v4f* hq = (const v4f*)&hsF[p][bl][0];
#pragma unroll 4
    for (int kk = 0; kk < 32; ++kk) {
      const int k4 = kbase + kk;
      const v4f hv = hq[k4];
      const v4f w0 = Wp[((k4 * 4 + 0) << 8)];
      const v4f w1 = Wp[((k4 * 4 + 1) << 8)];
      const v4f w2 = Wp[((k4 * 4 + 2) << 8)];
      const v4f w3 = Wp[((k4 * 4 + 3) << 8)];
      ai += w0.x * hv.x + w1.x * hv.y + w2.x * hv.z + w3.x * hv.w;
      af += w0.y * hv.x + w1.y * hv.y + w2.y * hv.z + w3.y * hv.w;
      ag += w0.z * hv.x + w1.z * hv.y + w2.z * hv.z + w3.z * hv.w;
      ao += w0.w * hv.x + w1.w * hv.y + w2.w * hv.z + w3.w * hv.w;
    }
    { const float t0 = __shfl_xor(ai, 32); ai += t0; }
    { const float t0 = __shfl_xor(af, 32); af += t0; }
    { const float t0 = __shfl_xor(ag, 32); ag += t0; }
    { const float t0 = __shfl_xor(ao, 32); ao += t0; }
    ai += ebi_ + wxi0 * xv.x + wxi1 * xv.y;
    af += ebf_ + wxf0 * xv.x + wxf1 * xv.y;
    ag += ebg_ + wxg0 * xv.x + wxg1 * xv.y;
    ao += ebo_ + wxo0 * xv.x + wxo1 * xv.y;
    const float iv = sigm(ai), fv = sigm(af), gv = tanhf(ag), ov = sigm(ao);
    c = fv * c + iv * gv;
    const float hn = ov * tanhf(c);
    if (lk == 0) {
      hsF[p ^ 1][bl][u] = hn;
      ((float*)encK4)[(((b << 6) + (u >> 2)) << 10) + (t << 2) + (u & 3)] = hn;
    }
    __syncthreads();
    p ^= 1;
  }

  // ---------------- decoder: 256 steps ----------------
  const float dbi_ = dBi[u] + dBh[u];
  const float dbf_ = dBi[256 + u] + dBh[256 + u];
  const float dbg_ = dBi[512 + u] + dBh[512 + u];
  const float dbo_ = dBi[768 + u] + dBh[768 + u];

  if (tid < 2) idxS[tid] = -1;
  if (tid < 512) maskC[tid >> 8][tid & 255] = 0;
  __syncthreads();

  for (int t = 0; t < 256; ++t) {
    // ---- stage dec_in = enc_out[b, idx] (or 0 at t=0) ----
    if (tid < 128) {
      const int bb = tid >> 6, k4s = tid & 63;
      const int ix = idxS[bb];
      v4f dv = (v4f)0.f;
      if (ix >= 0)
        dv = encK4[(((((blockIdx.x << 1) + bb) << 6) + k4s) << 8) + ix];
      ((v4f*)dinF)[tid] = dv;
    }
    __syncthreads();                      // B1: din ready

    // ---- decoder LSTM cell (K=256 split across the two wave halves) ----
    float ai = 0.f, af = 0.f, ag = 0.f, ao = 0.f;
    const v4f* Wi = decWi4 + u;
    const v4f* Wh = decWh4 + u;
    const v4f* hq = (const v4f*)&hsF[p][bl][0];
    const v4f* dq = (const v4f*)&dinF[bl][0];
#pragma unroll 2
    for (int kk = 0; kk < 32; ++kk) {
      const int k4 = kbase + kk;
      const v4f hv = hq[k4];
      const v4f dv = dq[k4];
      const v4f i0 = Wi[((k4 * 4 + 0) << 8)];
      const v4f i1 = Wi[((k4 * 4 + 1) << 8)];
      const v4f i2 = Wi[((k4 * 4 + 2) << 8)];
      const v4f i3 = Wi[((k4 * 4 + 3) << 8)];
      const v4f h0 = Wh[((k4 * 4 + 0) << 8)];
      const v4f h1 = Wh[((k4 * 4 + 1) << 8)];
      const v4f h2 = Wh[((k4 * 4 + 2) << 8)];
      const v4f h3 = Wh[((k4 * 4 + 3) << 8)];
      ai += i0.x * dv.x + i1.x * dv.y + i2.x * dv.z + i3.x * dv.w;
      ai += h0.x * hv.x + h1.x * hv.y + h2.x * hv.z + h3.x * hv.w;
      af += i0.y * dv.x + i1.y * dv.y + i2.y * dv.z + i3.y * dv.w;
      af += h0.y * hv.x + h1.y * hv.y + h2.y * hv.z + h3.y * hv.w;
      ag += i0.z * dv.x + i1.z * dv.y + i2.z * dv.z + i3.z * dv.w;
      ag += h0.z * hv.x + h1.z * hv.y + h2.z * hv.z + h3.z * hv.w;
      ao += i0.w * dv.x + i1.w * dv.y + i2.w * dv.z + i3.w * dv.w;
      ao += h0.w * hv.x + h1.w * hv.y + h2.w * hv.z + h3.w * hv.w;
    }
    { const float t0 = __shfl_xor(ai, 32); ai += t0; }
    { const float t0 = __shfl_xor(af, 32); af += t0; }
    { const float t0 = __shfl_xor(ag, 32); ag += t0; }
    { const float t0 = __shfl_xor(ao, 32); ao += t0; }
    ai += dbi_; af += dbf_; ag += dbg_; ao += dbo_;
    const float iv = sigm(ai), fv = sigm(af), gv = tanhf(ag), ov = sigm(ao);
    c = fv * c + iv * gv;
    const float hn = ov * tanhf(c);
    if (lk == 0) hsF[p ^ 1][bl][u] = hn;
    __syncthreads();                      // B2: new h ready
    p ^= 1;

    // ---- attention scores + gumbel sampling ----
    const int s = u;
    float sc = 0.f;
    const v4f* hq2 = (const v4f*)&hsF[p][bl][0];
    const v4f* E = encK4 + (b << 14) + s;
#pragma unroll 8
    for (int kk = 0; kk < 32; ++kk) {
      const int k4 = kbase + kk;
      const v4f ev = E[k4 << 8];
      const v4f hv = hq2[k4];
      sc += ev.x * hv.x + ev.y * hv.y + ev.z * hv.z + ev.w * hv.w;
    }
    { const float t0 = __shfl_xor(sc, 32); sc += t0; }
    // threefry2x32 partitionable: key_t = tf2(key42; 0,t); bits = x0^x1
    unsigned bits;
    {
      unsigned kk0 = 0u, kk1 = (unsigned)t;
      tf2(0u, 42u, kk0, kk1);
      unsigned y0 = 0u, y1 = (unsigned)((b << 8) + s);
      tf2(kk0, kk1, y0, y1);
      bits = y0 ^ y1;
    }
    const float fr = __uint_as_float((bits >> 9) | 0x3f800000u) - 1.0f;
    const float uu = (fr > 0.f) ? fr : 1.17549435e-38f;
    const float gum = -logf(-logf(uu));
    const float NEG_INF = __int_as_float((int)0xff800000);
    float bv = maskC[bl][s] ? NEG_INF : (sc + gum);
    int bi = s;
    // wave argmax, first-index tie-break (both K-halves hold identical pairs)
#pragma unroll
    for (int off = 32; off; off >>= 1) {
      const float ov2 = __shfl_xor(bv, off, 64);
      const int oi2 = __shfl_xor(bi, off, 64);
      if (ov2 > bv || (ov2 == bv && oi2 < bi)) { bv = ov2; bi = oi2; }
    }
    if (l == 0) { partV[bl][wl] = bv; partI[bl][wl] = bi; }
    __syncthreads();                      // B3: wave partials ready
    if ((tid & 511) == 0) {               // tid 0 -> bl 0, tid 512 -> bl 1
      float v = partV[bl][0]; int fi = partI[bl][0];
#pragma unroll
      for (int j = 1; j < 8; ++j) {
        const float vj = partV[bl][j];
        if (vj > v) { v = vj; fi = partI[bl][j]; }
      }
      idxS[bl] = fi;
      maskC[bl][fi] = 1;
      out[(b << 8) + t] = fi;
    }
    __syncthreads();                      // B4: idx/mask ready for staging
  }
}

extern "C" void kernel_launch(void* const* d_in, const int* in_sizes, int n_in,
                              void* d_out, int out_size, void* d_ws, size_t ws_size,
                              hipStream_t stream) {
  (void)in_sizes; (void)n_in; (void)out_size;
  if (ws_size < WS_NEEDED) return;   // need ~139 MB scratch

  const float* inp = (const float*)d_in[0];
  const float* eWi = (const float*)d_in[1];
  const float* eWh = (const float*)d_in[2];
  const float* eBi = (const float*)d_in[3];
  const float* eBh = (const float*)d_in[4];
  const float* dWi = (const float*)d_in[5];
  const float* dWh = (const float*)d_in[6];
  const float* dBi = (const float*)d_in[7];
  const float* dBh = (const float*)d_in[8];
  int* out = (int*)d_out;
  float* wsf = (float*)d_ws;

  hipLaunchKernelGGL(repack_k, dim3(256), dim3(256), 0, stream, eWh, dWi, dWh, wsf);
  hipLaunchKernelGGL(ptrnet_kernel, dim3(256), dim3(1024), 0, stream,
                     inp, eWi, eBi, eBh, dBi, dBh, out, wsf);
}

// Round 4
// 11764.209 us; speedup vs baseline: 1.6401x; 1.6401x over previous
//
#include <hip/hip_runtime.h>
#include <cstdint>
#include <cstddef>

// ============================================================================
// PointerNet: encoder LSTM (B=512,S=256,D=2,H=256) + autoregressive pointer
// decode with jax.random.categorical (threefry2x32 partitionable, key 42).
// Output: int32 indices [512][256], trajectory-exact vs JAX reference.
//
// R4 structure: grid = 128 blocks x 1024 threads, 4 batches per block.
// Rationale (R3 post-mortem): R2/R3 were L2-BW-bound on redundant weight
// streams (4 MB/CU/step -> 128 MB/XCD/step ~= 30 us/step = measured step
// time). Here each weight float4 is read ONCE per block: waves partition
// (K-quarter x u-slice); each lane FMAs its weights against all 4 batches'
// h/din (LDS broadcasts); partial gate sums reduced via LDS; thread t=(b,u)
// owns the activation + cell state c in a register for the whole kernel.
// Decoder weight traffic: 32 MB/XCD/step (~7.4 us) ~= balanced with VALU
// (~6.8 us). Attention skips masked positions (~50% traffic saved).
// ============================================================================

typedef float v4f __attribute__((ext_vector_type(4)));

#define WS_ENCW4_OFF  (2u << 20)                    // [256 k][256 u][4 g] f32
#define WS_DECWI4_OFF (3u << 20)
#define WS_DECWH4_OFF (4u << 20)
#define WS_ENCK4_OFF  (5u << 20)                    // [512 b][64 u4][256 s][4] f32
#define WS_NEEDED     ((size_t)(5u << 20) + (size_t)512 * 64 * 256 * 16)

__device__ __forceinline__ unsigned rotl32(unsigned x, int r) {
  return (x << r) | (x >> (32 - r));
}
__device__ __forceinline__ float sigm(float x) { return 1.f / (1.f + expf(-x)); }

// Threefry-2x32, 20 rounds (jax._src.prng schedule) — verified exact R1-R3.
__device__ __forceinline__ void tf2(unsigned k0, unsigned k1,
                                    unsigned& x0, unsigned& x1) {
  const unsigned k2 = k0 ^ k1 ^ 0x1BD11BDAu;
  x0 += k0; x1 += k1;
  x0 += x1; x1 = rotl32(x1, 13); x1 ^= x0;
  x0 += x1; x1 = rotl32(x1, 15); x1 ^= x0;
  x0 += x1; x1 = rotl32(x1, 26); x1 ^= x0;
  x0 += x1; x1 = rotl32(x1,  6); x1 ^= x0;
  x0 += k1; x1 += k2 + 1u;
  x0 += x1; x1 = rotl32(x1, 17); x1 ^= x0;
  x0 += x1; x1 = rotl32(x1, 29); x1 ^= x0;
  x0 += x1; x1 = rotl32(x1, 16); x1 ^= x0;
  x0 += x1; x1 = rotl32(x1, 24); x1 ^= x0;
  x0 += k2; x1 += k0 + 2u;
  x0 += x1; x1 = rotl32(x1, 13); x1 ^= x0;
  x0 += x1; x1 = rotl32(x1, 15); x1 ^= x0;
  x0 += x1; x1 = rotl32(x1, 26); x1 ^= x0;
  x0 += x1; x1 = rotl32(x1,  6); x1 ^= x0;
  x0 += k0; x1 += k1 + 3u;
  x0 += x1; x1 = rotl32(x1, 17); x1 ^= x0;
  x0 += x1; x1 = rotl32(x1, 29); x1 ^= x0;
  x0 += x1; x1 = rotl32(x1, 16); x1 ^= x0;
  x0 += x1; x1 = rotl32(x1, 24); x1 ^= x0;
  x0 += k1; x1 += k2 + 4u;
  x0 += x1; x1 = rotl32(x1, 13); x1 ^= x0;
  x0 += x1; x1 = rotl32(x1, 15); x1 ^= x0;
  x0 += x1; x1 = rotl32(x1, 26); x1 ^= x0;
  x0 += x1; x1 = rotl32(x1,  6); x1 ^= x0;
  x0 += k2; x1 += k0 + 5u;
}

// Repack W [1024 rows][256 k] row-major -> [k][u][gate] (float4 per (k,u)).
__global__ void repack_k(const float* __restrict__ eWh,
                         const float* __restrict__ dWi,
                         const float* __restrict__ dWh,
                         float* __restrict__ ws) {
  float* encW4 = (float*)((char*)ws + WS_ENCW4_OFF);
  float* decWi4 = (float*)((char*)ws + WS_DECWI4_OFF);
  float* decWh4 = (float*)((char*)ws + WS_DECWH4_OFF);
  const int n = blockIdx.x * blockDim.x + threadIdx.x;   // 65536 = 256k x 256u
  if (n >= 65536) return;
  const int k = n >> 8, u = n & 255;
#pragma unroll
  for (int g = 0; g < 4; ++g) {
    const int src = ((g << 8) + u) * 256 + k;
    const int dst = (n << 2) + g;
    encW4[dst] = eWh[src];
    decWi4[dst] = dWi[src];
    decWh4[dst] = dWh[src];
  }
}

__global__ void __launch_bounds__(1024)
ptrnet_kernel(const float* __restrict__ inp,    // [512][256][2]
              const float* __restrict__ eWi,    // [1024][2]
              const float* __restrict__ eBi, const float* __restrict__ eBh,
              const float* __restrict__ dBi, const float* __restrict__ dBh,
              int* __restrict__ out,            // [512][256]
              float* __restrict__ ws) {
  const int tid  = threadIdx.x;
  const int wave = tid >> 6, l = tid & 63;
  const int kq   = wave >> 2;               // K-quarter 0..3 (16 k4 each)
  const int uw   = wave & 3;                // u-slice 0..3
  const int uP   = (uw << 6) | l;           // this lane's unit in P1 (matmul)
  const int k4b  = kq << 4;
  const int bA   = tid >> 8;                // this thread's batch in P2/attn
  const int uA   = tid & 255;               // this thread's unit/score in P2/attn
  const int b0   = blockIdx.x << 2;
  const int bG   = b0 + bA;

  const v4f* encW4  = (const v4f*)((char*)ws + WS_ENCW4_OFF);
  const v4f* decWi4 = (const v4f*)((char*)ws + WS_DECWI4_OFF);
  const v4f* decWh4 = (const v4f*)((char*)ws + WS_DECWH4_OFF);
  v4f* encK4 = (v4f*)((char*)ws + WS_ENCK4_OFF);

  __shared__ __align__(16) float hsF[2][1024];   // h dbuf: [buf][b*256+u]
  __shared__ __align__(16) v4f dinV[256];        // dec_in [b][64 k4]
  __shared__ __align__(16) v4f red[16][256];     // partials [kq*4+b][u] (gates)
  __shared__ unsigned char maskC[4][256];
  __shared__ float partV[4][4];
  __shared__ int   partI[4][4];
  __shared__ int   idxS[4];

  // ---- activation-thread constants (keyed by uA) ----
  const float ebi_ = eBi[uA] + eBh[uA];
  const float ebf_ = eBi[256 + uA] + eBh[256 + uA];
  const float ebg_ = eBi[512 + uA] + eBh[512 + uA];
  const float ebo_ = eBi[768 + uA] + eBh[768 + uA];
  const float wxi0 = eWi[2 * uA], wxi1 = eWi[2 * uA + 1];
  const float wxf0 = eWi[2 * (256 + uA)], wxf1 = eWi[2 * (256 + uA) + 1];
  const float wxg0 = eWi[2 * (512 + uA)], wxg1 = eWi[2 * (512 + uA) + 1];
  const float wxo0 = eWi[2 * (768 + uA)], wxo1 = eWi[2 * (768 + uA) + 1];

  hsF[0][tid] = 0.f;
  __syncthreads();

  float c = 0.f;        // cell state for (bG, uA) — register-resident throughout
  int p = 0;

  // ---------------- encoder: 256 steps ----------------
  for (int t = 0; t < 256; ++t) {
    // P1: Wh·h partials for this (kq, u) over all 4 batches
    v4f a0 = (v4f)0.f, a1 = (v4f)0.f, a2 = (v4f)0.f, a3 = (v4f)0.f;
    const v4f* Wp = encW4 + uP;
    const v4f* hq = (const v4f*)&hsF[p][0];       // [4 b][64 k4]
#pragma unroll 2
    for (int kk = 0; kk < 16; ++kk) {
      const int k4 = k4b + kk;
      const v4f w0 = Wp[(k4 * 4 + 0) << 8];
      const v4f w1 = Wp[(k4 * 4 + 1) << 8];
      const v4f w2 = Wp[(k4 * 4 + 2) << 8];
      const v4f w3 = Wp[(k4 * 4 + 3) << 8];
      const v4f h0 = hq[k4];
      const v4f h1 = hq[64 + k4];
      const v4f h2 = hq[128 + k4];
      const v4f h3 = hq[192 + k4];
      a0 += w0 * h0.x + w1 * h0.y + w2 * h0.z + w3 * h0.w;
      a1 += w0 * h1.x + w1 * h1.y + w2 * h1.z + w3 * h1.w;
      a2 += w0 * h2.x + w1 * h2.y + w2 * h2.z + w3 * h2.w;
      a3 += w0 * h3.x + w1 * h3.y + w2 * h3.z + w3 * h3.w;
    }
    red[(kq << 2) | 0][uP] = a0;
    red[(kq << 2) | 1][uP] = a1;
    red[(kq << 2) | 2][uP] = a2;
    red[(kq << 2) | 3][uP] = a3;
    __syncthreads();                              // S_B: partials ready
    // P2: activation for (bA, uA)
    const v4f gv = red[bA][uA] + red[4 + bA][uA] + red[8 + bA][uA] + red[12 + bA][uA];
    const float2 xv = *(const float2*)(inp + (((bG) << 8) + t) * 2);
    const float ai = gv.x + ebi_ + wxi0 * xv.x + wxi1 * xv.y;
    const float af = gv.y + ebf_ + wxf0 * xv.x + wxf1 * xv.y;
    const float ag = gv.z + ebg_ + wxg0 * xv.x + wxg1 * xv.y;
    const float ao = gv.w + ebo_ + wxo0 * xv.x + wxo1 * xv.y;
    const float iv = sigm(ai), fv = sigm(af), gva = tanhf(ag), ov = sigm(ao);
    c = fv * c + iv * gva;
    const float hn = ov * tanhf(c);
    hsF[p ^ 1][(bA << 8) | uA] = hn;
    ((float*)encK4)[(((bG << 6) + (uA >> 2)) << 10) + (t << 2) + (uA & 3)] = hn;
    __syncthreads();                              // S_C: new h ready
    p ^= 1;
  }

  // ---------------- decoder: 256 steps ----------------
  const float dbi_ = dBi[uA] + dBh[uA];
  const float dbf_ = dBi[256 + uA] + dBh[256 + uA];
  const float dbg_ = dBi[512 + uA] + dBh[512 + uA];
  const float dbo_ = dBi[768 + uA] + dBh[768 + uA];
  const float NEG_INF = __int_as_float((int)0xff800000);

  if (tid < 4) idxS[tid] = -1;
  maskC[bA][uA] = 0;
  __syncthreads();

  for (int t = 0; t < 256; ++t) {
    // stage dec_in = enc_out[b, idx] (0 at t=0)
    if (tid < 256) {
      const int bb = tid >> 6, k4 = tid & 63;
      const int ix = idxS[bb];
      v4f dv = (v4f)0.f;
      if (ix >= 0) dv = encK4[((((b0 + bb) << 6) | k4) << 8) + ix];
      dinV[tid] = dv;
    }
    __syncthreads();                              // S_A: din ready

    // P1: Wh·h + Wi·din partials (two sweeps keep VGPR pressure low)
    v4f a0 = (v4f)0.f, a1 = (v4f)0.f, a2 = (v4f)0.f, a3 = (v4f)0.f;
    {
      const v4f* Wh = decWh4 + uP;
      const v4f* hq = (const v4f*)&hsF[p][0];
#pragma unroll 2
      for (int kk = 0; kk < 16; ++kk) {
        const int k4 = k4b + kk;
        const v4f w0 = Wh[(k4 * 4 + 0) << 8];
        const v4f w1 = Wh[(k4 * 4 + 1) << 8];
        const v4f w2 = Wh[(k4 * 4 + 2) << 8];
        const v4f w3 = Wh[(k4 * 4 + 3) << 8];
        const v4f h0 = hq[k4];
        const v4f h1 = hq[64 + k4];
        const v4f h2 = hq[128 + k4];
        const v4f h3 = hq[192 + k4];
        a0 += w0 * h0.x + w1 * h0.y + w2 * h0.z + w3 * h0.w;
        a1 += w0 * h1.x + w1 * h1.y + w2 * h1.z + w3 * h1.w;
        a2 += w0 * h2.x + w1 * h2.y + w2 * h2.z + w3 * h2.w;
        a3 += w0 * h3.x + w1 * h3.y + w2 * h3.z + w3 * h3.w;
      }
    }
    {
      const v4f* Wi = decWi4 + uP;
#pragma unroll 2
      for (int kk = 0; kk < 16; ++kk) {
        const int k4 = k4b + kk;
        const v4f w0 = Wi[(k4 * 4 + 0) << 8];
        const v4f w1 = Wi[(k4 * 4 + 1) << 8];
        const v4f w2 = Wi[(k4 * 4 + 2) << 8];
        const v4f w3 = Wi[(k4 * 4 + 3) << 8];
        const v4f d0 = dinV[k4];
        const v4f d1 = dinV[64 + k4];
        const v4f d2 = dinV[128 + k4];
        const v4f d3 = dinV[192 + k4];
        a0 += w0 * d0.x + w1 * d0.y + w2 * d0.z + w3 * d0.w;
        a1 += w0 * d1.x + w1 * d1.y + w2 * d1.z + w3 * d1.w;
        a2 += w0 * d2.x + w1 * d2.y + w2 * d2.z + w3 * d2.w;
        a3 += w0 * d3.x + w1 * d3.y + w2 * d3.z + w3 * d3.w;
      }
    }
    red[(kq << 2) | 0][uP] = a0;
    red[(kq << 2) | 1][uP] = a1;
    red[(kq << 2) | 2][uP] = a2;
    red[(kq << 2) | 3][uP] = a3;
    __syncthreads();                              // S_B: partials ready

    // P2: activation for (bA, uA)
    const v4f gv = red[bA][uA] + red[4 + bA][uA] + red[8 + bA][uA] + red[12 + bA][uA];
    const float ai = gv.x + dbi_;
    const float af = gv.y + dbf_;
    const float ag = gv.z + dbg_;
    const float ao = gv.w + dbo_;
    const float iv = sigm(ai), fv = sigm(af), gva = tanhf(ag), ov = sigm(ao);
    c = fv * c + iv * gva;
    const float hn = ov * tanhf(c);
    hsF[p ^ 1][(bA << 8) | uA] = hn;
    __syncthreads();                              // S_C: new h ready
    p ^= 1;

    // attention + gumbel sampling: thread (bA, s=uA)
    const int s = uA;
    const int masked = maskC[bA][s];
    float sc = 0.f;
    if (!masked) {
      const v4f* E = encK4 + (bG << 14) + s;
      const v4f* hq2 = ((const v4f*)&hsF[p][0]) + (bA << 6);
#pragma unroll 4
      for (int k4 = 0; k4 < 64; ++k4) {
        const v4f ev = E[k4 << 8];
        const v4f hv = hq2[k4];
        sc += ev.x * hv.x + ev.y * hv.y + ev.z * hv.z + ev.w * hv.w;
      }
    }
    // threefry2x32 partitionable: key_t = tf2(key42; 0,t); bits = x0^x1
    unsigned bits;
    {
      unsigned kk0 = 0u, kk1 = (unsigned)t;
      tf2(0u, 42u, kk0, kk1);
      unsigned y0 = 0u, y1 = (unsigned)((bG << 8) + s);
      tf2(kk0, kk1, y0, y1);
      bits = y0 ^ y1;
    }
    const float fr = __uint_as_float((bits >> 9) | 0x3f800000u) - 1.0f;
    const float uu = (fr > 0.f) ? fr : 1.17549435e-38f;
    const float gum = -logf(-logf(uu));
    float bv = masked ? NEG_INF : (sc + gum);
    int bi = s;
    // wave argmax, first-index tie-break (matches jnp.argmax)
#pragma unroll
    for (int off = 32; off; off >>= 1) {
      const float ov2 = __shfl_xor(bv, off, 64);
      const int oi2 = __shfl_xor(bi, off, 64);
      if (ov2 > bv || (ov2 == bv && oi2 < bi)) { bv = ov2; bi = oi2; }
    }
    if (l == 0) { partV[bA][uw] = bv; partI[bA][uw] = bi; }
    __syncthreads();                              // S_D: wave partials ready
    // final cross-chunk argmax, computed redundantly by all threads of batch
    float v = partV[bA][0]; int fi = partI[bA][0];
#pragma unroll
    for (int j = 1; j < 4; ++j) {
      const float vj = partV[bA][j];
      if (vj > v) { v = vj; fi = partI[bA][j]; }   // strict > keeps lowest s
    }
    if (uA == 0) { idxS[bA] = fi; out[(bG << 8) + t] = fi; }
    if (uA == fi) maskC[bA][uA] = 1;
    __syncthreads();                              // S_E: idx/mask ready
  }
}

extern "C" void kernel_launch(void* const* d_in, const int* in_sizes, int n_in,
                              void* d_out, int out_size, void* d_ws, size_t ws_size,
                              hipStream_t stream) {
  (void)in_sizes; (void)n_in; (void)out_size;
  if (ws_size < WS_NEEDED) return;   // need ~139 MB scratch

  const float* inp = (const float*)d_in[0];
  const float* eWi = (const float*)d_in[1];
  const float* eWh = (const float*)d_in[2];
  const float* eBi = (const float*)d_in[3];
  const float* eBh = (const float*)d_in[4];
  const float* dWi = (const float*)d_in[5];
  const float* dWh = (const float*)d_in[6];
  const float* dBi = (const float*)d_in[7];
  const float* dBh = (const float*)d_in[8];
  int* out = (int*)d_out;
  float* wsf = (float*)d_ws;

  hipLaunchKernelGGL(repack_k, dim3(256), dim3(256), 0, stream, eWh, dWi, dWh, wsf);
  hipLaunchKernelGGL(ptrnet_kernel, dim3(128), dim3(1024), 0, stream,
                     inp, eWi, eBi, eBh, dBi, dBh, out, wsf);
}